// Round 3
// baseline (7244.133 us; speedup 1.0000x reference)
//
#include <hip/hip_runtime.h>
#include <hip/hip_bf16.h>

#define BATCH 64
#define SEQ   2048
#define ISZ   256
#define H     256
#define G4    1024            // 4*H
#define M_TOT (BATCH*SEQ)     // 131072

typedef _Float16 half8  __attribute__((ext_vector_type(8)));
typedef _Float16 half4v __attribute__((ext_vector_type(4)));
typedef _Float16 half2v __attribute__((ext_vector_type(2)));
typedef float    f32x4  __attribute__((ext_vector_type(4)));

union U32H2 { unsigned int u; half2v h; };
static __device__ __forceinline__ half2v u2h(unsigned int u){ U32H2 x; x.u = u; return x.h; }

#if __has_builtin(__builtin_amdgcn_fdot2)
#define FDOT2(w,hp,acc) __builtin_amdgcn_fdot2(u2h(w), u2h(hp), (acc), false)
#else
static __device__ __forceinline__ float fdot2_sw(unsigned int w, unsigned int hp, float acc){
  half2v wv = u2h(w), hv = u2h(hp);
  return acc + (float)wv[0]*(float)hv[0] + (float)wv[1]*(float)hv[1];
}
#define FDOT2(w,hp,acc) fdot2_sw((w),(hp),(acc))
#endif

// ---------------------------------------------------------------------------
// Prep: f16-convert W_ih, pack W_hh into k2-major f16 pairs, fuse biases.
// Wpk[k2*1024 + n] = (f16)W_hh[n][2k2] | (f16)W_hh[n][2k2+1] << 16
// ---------------------------------------------------------------------------
__global__ __launch_bounds__(256) void prep_kernel(
    const float* __restrict__ Wih, const float* __restrict__ Whh,
    const float* __restrict__ bih, const float* __restrict__ bhh,
    _Float16* __restrict__ Wihf, unsigned int* __restrict__ Wpk,
    float* __restrict__ bias) {
  const int idx = blockIdx.x * 256 + threadIdx.x;     // grid covers 262144 exactly
  Wihf[idx] = (_Float16)Wih[idx];
  if (idx < 131072) {
    const int n = idx & 1023, k2 = idx >> 10;
    U32H2 p;
    p.h[0] = (_Float16)Whh[n*256 + 2*k2];
    p.h[1] = (_Float16)Whh[n*256 + 2*k2 + 1];
    Wpk[idx] = p.u;
  }
  if (idx < 1024) bias[idx] = bih[idx] + bhh[idx];
}

// ---------------------------------------------------------------------------
// Phase 1: x_proj GEMM (f16 MFMA, 128x128 tile). Epilogue stores XP with
// PERMUTED columns: np = 4*(n&255) + (n>>8), so the scan's thread t reads its
// {i,f,g,o} pre-activations for element t as one contiguous 8B half4.
// ---------------------------------------------------------------------------
#define BM 128
#define BN 128
#define BK 32
#define LDA 40

__global__ __launch_bounds__(256) void xproj_gemm(
    const float* __restrict__ X, const _Float16* __restrict__ Wihf,
    const float* __restrict__ bias, _Float16* __restrict__ XP) {
  __shared__ _Float16 As[BM*LDA];
  __shared__ _Float16 Bs[BN*LDA];
  const int tid  = threadIdx.x;
  const int m0   = blockIdx.x * BM;
  const int n0   = blockIdx.y * BN;
  const int lane = tid & 63;
  const int w    = tid >> 6;
  const int wm   = w & 1, wn = w >> 1;
  const int row  = tid >> 1, hlf = tid & 1;   // staging map: 2 threads/row

  f32x4 acc[4][4];
  #pragma unroll
  for (int mi = 0; mi < 4; ++mi)
    #pragma unroll
    for (int ni = 0; ni < 4; ++ni)
      acc[mi][ni] = (f32x4){0.f, 0.f, 0.f, 0.f};

  for (int kt = 0; kt < ISZ/BK; ++kt) {
    const int k0 = kt * BK;
    __syncthreads();
    {
      const float4* pa = (const float4*)(X + (size_t)(m0+row)*ISZ + k0 + hlf*16);
      float4 f0 = pa[0], f1 = pa[1], f2 = pa[2], f3 = pa[3];
      half8 h0, h1;
      h0[0]=(_Float16)f0.x; h0[1]=(_Float16)f0.y; h0[2]=(_Float16)f0.z; h0[3]=(_Float16)f0.w;
      h0[4]=(_Float16)f1.x; h0[5]=(_Float16)f1.y; h0[6]=(_Float16)f1.z; h0[7]=(_Float16)f1.w;
      h1[0]=(_Float16)f2.x; h1[1]=(_Float16)f2.y; h1[2]=(_Float16)f2.z; h1[3]=(_Float16)f2.w;
      h1[4]=(_Float16)f3.x; h1[5]=(_Float16)f3.y; h1[6]=(_Float16)f3.z; h1[7]=(_Float16)f3.w;
      *(half8*)&As[row*LDA + hlf*16]     = h0;
      *(half8*)&As[row*LDA + hlf*16 + 8] = h1;
      const half8* pb = (const half8*)(Wihf + (size_t)(n0+row)*ISZ + k0 + hlf*16);
      half8 b0 = pb[0], b1 = pb[1];
      *(half8*)&Bs[row*LDA + hlf*16]     = b0;
      *(half8*)&Bs[row*LDA + hlf*16 + 8] = b1;
    }
    __syncthreads();
    const int kch = (lane >> 4) * 8;
    const int rm  = wm*64 + (lane & 15);
    const int rn  = wn*64 + (lane & 15);
    half8 af[4], bf[4];
    #pragma unroll
    for (int i = 0; i < 4; ++i) {
      af[i] = *(const half8*)&As[(rm + i*16)*LDA + kch];
      bf[i] = *(const half8*)&Bs[(rn + i*16)*LDA + kch];
    }
    #pragma unroll
    for (int mi = 0; mi < 4; ++mi)
      #pragma unroll
      for (int ni = 0; ni < 4; ++ni)
        acc[mi][ni] = __builtin_amdgcn_mfma_f32_16x16x32_f16(af[mi], bf[ni], acc[mi][ni], 0, 0, 0);
  }
  const int col = lane & 15, qr = (lane >> 4) * 4;
  #pragma unroll
  for (int ni = 0; ni < 4; ++ni) {
    const int n  = n0 + wn*64 + ni*16 + col;
    const int np = ((n & 255) << 2) | (n >> 8);     // gate-interleaved column
    const float bs = bias[n];
    #pragma unroll
    for (int mi = 0; mi < 4; ++mi) {
      #pragma unroll
      for (int r = 0; r < 4; ++r) {
        const int m = m0 + wm*64 + mi*16 + qr + r;
        XP[(size_t)m*G4 + np] = (_Float16)(acc[mi][ni][r] + bs);
      }
    }
  }
}

// ---------------------------------------------------------------------------
// Phase 2: scan. 64 WGs x 256 threads, 1 wave/SIMD (VGPR cap 512). Thread t
// owns gate rows {t, 256+t, 512+t, 768+t} == all 4 gates of h-element t, so
// i/f/g/o combine LOCALLY (no act exchange). Weights: per row 100 f16-pair
// words in VGPRs (4x100=400) + 28 in LDS (114.7 KB). h double-buffered as
// packed f16 pairs in LDS -> ONE barrier per step.
// ---------------------------------------------------------------------------
#define NRV 100                 // VGPR-resident pair-words per row
#define NLQ 7                   // LDS-resident uint4-chunks per row (7*4=28)

__global__ __launch_bounds__(256, 1) void lstm_scan(
    const _Float16* __restrict__ XP, const unsigned int* __restrict__ Wpk,
    float* __restrict__ out) {
  __shared__ uint4 wlds[4*NLQ*256];       // [(r*7+q)][t], 114688 B
  __shared__ unsigned int hbuf[2][H/2];   // h as packed f16 pairs, dbl-buffered
  const int t = threadIdx.x;
  const int b = blockIdx.x;

  // ---- stage weights: 400 words -> VGPRs, 112 words -> LDS ----
  unsigned int wreg[4*NRV];
  #pragma unroll
  for (int r = 0; r < 4; ++r)
    #pragma unroll
    for (int i = 0; i < NRV; ++i)
      wreg[r*NRV + i] = Wpk[i*1024 + r*256 + t];
  #pragma unroll
  for (int r = 0; r < 4; ++r)
    #pragma unroll
    for (int q = 0; q < NLQ; ++q) {
      uint4 v;
      v.x = Wpk[(NRV + 4*q + 0)*1024 + r*256 + t];
      v.y = Wpk[(NRV + 4*q + 1)*1024 + r*256 + t];
      v.z = Wpk[(NRV + 4*q + 2)*1024 + r*256 + t];
      v.w = Wpk[(NRV + 4*q + 3)*1024 + r*256 + t];
      wlds[(r*NLQ + q)*256 + t] = v;
    }
  if (t < H/2) { hbuf[0][t] = 0u; hbuf[1][t] = 0u; }

  float c = 0.f;
  const _Float16* xb = XP + (size_t)b*SEQ*G4 + 4*t;
  half4v xp4 = *(const half4v*)xb;        // step 0 pre-activations {i,f,g,o}
  float* outb = out + (size_t)b*SEQ*H + t;
  __syncthreads();

  int cur = 0;
  #pragma unroll 1
  for (int s = 0; s < SEQ; ++s) {
    const int sn = (s + 1 < SEQ) ? (s + 1) : s;
    const half4v xnext = *(const half4v*)(xb + (size_t)sn * G4);  // prefetch

    float aA0 = (float)xp4[0], aA1 = (float)xp4[1], aA2 = (float)xp4[2], aA3 = (float)xp4[3];
    float aB0 = 0.f, aB1 = 0.f, aB2 = 0.f, aB3 = 0.f;
    const unsigned int* hc = hbuf[cur];
    #pragma unroll
    for (int q = 0; q < NRV/4; ++q) {     // k2 = 0..99 from VGPRs
      uint4 hq = *(const uint4*)(hc + 4*q);
      aA0 = FDOT2(wreg[0*NRV+4*q+0], hq.x, aA0);
      aA1 = FDOT2(wreg[1*NRV+4*q+0], hq.x, aA1);
      aA2 = FDOT2(wreg[2*NRV+4*q+0], hq.x, aA2);
      aA3 = FDOT2(wreg[3*NRV+4*q+0], hq.x, aA3);
      aB0 = FDOT2(wreg[0*NRV+4*q+1], hq.y, aB0);
      aB1 = FDOT2(wreg[1*NRV+4*q+1], hq.y, aB1);
      aB2 = FDOT2(wreg[2*NRV+4*q+1], hq.y, aB2);
      aB3 = FDOT2(wreg[3*NRV+4*q+1], hq.y, aB3);
      aA0 = FDOT2(wreg[0*NRV+4*q+2], hq.z, aA0);
      aA1 = FDOT2(wreg[1*NRV+4*q+2], hq.z, aA1);
      aA2 = FDOT2(wreg[2*NRV+4*q+2], hq.z, aA2);
      aA3 = FDOT2(wreg[3*NRV+4*q+2], hq.z, aA3);
      aB0 = FDOT2(wreg[0*NRV+4*q+3], hq.w, aB0);
      aB1 = FDOT2(wreg[1*NRV+4*q+3], hq.w, aB1);
      aB2 = FDOT2(wreg[2*NRV+4*q+3], hq.w, aB2);
      aB3 = FDOT2(wreg[3*NRV+4*q+3], hq.w, aB3);
    }
    #pragma unroll
    for (int q = 0; q < NLQ; ++q) {       // k2 = 100..127 from LDS
      uint4 hq = *(const uint4*)(hc + NRV + 4*q);
      uint4 w0 = wlds[(0*NLQ + q)*256 + t];
      uint4 w1 = wlds[(1*NLQ + q)*256 + t];
      uint4 w2 = wlds[(2*NLQ + q)*256 + t];
      uint4 w3 = wlds[(3*NLQ + q)*256 + t];
      aA0 = FDOT2(w0.x, hq.x, aA0);  aB0 = FDOT2(w0.y, hq.y, aB0);
      aA0 = FDOT2(w0.z, hq.z, aA0);  aB0 = FDOT2(w0.w, hq.w, aB0);
      aA1 = FDOT2(w1.x, hq.x, aA1);  aB1 = FDOT2(w1.y, hq.y, aB1);
      aA1 = FDOT2(w1.z, hq.z, aA1);  aB1 = FDOT2(w1.w, hq.w, aB1);
      aA2 = FDOT2(w2.x, hq.x, aA2);  aB2 = FDOT2(w2.y, hq.y, aB2);
      aA2 = FDOT2(w2.z, hq.z, aA2);  aB2 = FDOT2(w2.w, hq.w, aB2);
      aA3 = FDOT2(w3.x, hq.x, aA3);  aB3 = FDOT2(w3.y, hq.y, aB3);
      aA3 = FDOT2(w3.z, hq.z, aA3);  aB3 = FDOT2(w3.w, hq.w, aB3);
    }
    const float gi = aA0 + aB0;
    const float gf = aA1 + aB1;
    const float gg = aA2 + aB2;
    const float go = aA3 + aB3;
    const float si = 1.f / (1.f + __expf(-gi));
    const float sf = 1.f / (1.f + __expf(-gf));
    const float tg = 2.f / (1.f + __expf(-2.f*gg)) - 1.f;
    const float so = 1.f / (1.f + __expf(-go));
    c = sf*c + si*tg;
    const float th = 2.f / (1.f + __expf(-2.f*c)) - 1.f;
    const float h = so*th;
    outb[(size_t)s*H] = h;
    ((_Float16*)hbuf[cur ^ 1])[t] = (_Float16)h;   // write NEXT buffer (no WAR)
    if (s == SEQ-1) {
      out[(size_t)BATCH*SEQ*H + (size_t)b*H + t] = h;                   // final h
      out[(size_t)BATCH*SEQ*H + (size_t)BATCH*H + (size_t)b*H + t] = c; // final c
    }
    xp4 = xnext;
    cur ^= 1;
    __syncthreads();
  }
}

// ---------------------------------------------------------------------------
// ws layout: [ XP f16 256MB | Wihf f16 512KB | Wpk u32 512KB | bias f32 4KB ]
// ---------------------------------------------------------------------------
extern "C" void kernel_launch(void* const* d_in, const int* in_sizes, int n_in,
                              void* d_out, int out_size, void* d_ws, size_t ws_size,
                              hipStream_t stream) {
  const float* x   = (const float*)d_in[0];
  const float* Wih = (const float*)d_in[1];
  const float* Whh = (const float*)d_in[2];
  const float* bih = (const float*)d_in[3];
  const float* bhh = (const float*)d_in[4];
  float* out = (float*)d_out;

  char* ws = (char*)d_ws;
  const size_t XP_BYTES = (size_t)M_TOT * G4 * sizeof(_Float16);   // 268435456
  _Float16*     XPp  = (_Float16*)ws;
  _Float16*     Wihf = (_Float16*)(ws + XP_BYTES);
  unsigned int* Wpk  = (unsigned int*)(ws + XP_BYTES + 524288);
  float*        bias = (float*)(ws + XP_BYTES + 1048576);

  prep_kernel<<<dim3(1024),            dim3(256), 0, stream>>>(Wih, Whh, bih, bhh, Wihf, Wpk, bias);
  xproj_gemm <<<dim3(M_TOT/BM, G4/BN), dim3(256), 0, stream>>>(x, Wihf, bias, XPp);
  lstm_scan  <<<dim3(BATCH),           dim3(256), 0, stream>>>(XPp, Wpk, out);
}

// Round 4
// 4249.828 us; speedup vs baseline: 1.7046x; 1.7046x over previous
//
#include <hip/hip_runtime.h>
#include <hip/hip_bf16.h>

#define BATCH 64
#define SEQ   2048
#define ISZ   256
#define H     256
#define G4    1024            // 4*H
#define M_TOT (BATCH*SEQ)     // 131072

typedef _Float16 half8  __attribute__((ext_vector_type(8)));
typedef _Float16 half4v __attribute__((ext_vector_type(4)));
typedef float    f32x4  __attribute__((ext_vector_type(4)));

#if __has_builtin(__builtin_amdgcn_sdot4)
#define SDOT4(a,b,c) __builtin_amdgcn_sdot4((int)(a), (int)(b), (c), false)
#else
static __device__ __forceinline__ int sdot4_sw(unsigned int a, unsigned int b, int c){
  #pragma unroll
  for (int i = 0; i < 4; ++i)
    c += (int)((signed char)((a >> (8*i)) & 0xff)) * (int)((signed char)((b >> (8*i)) & 0xff));
  return c;
}
#define SDOT4(a,b,c) sdot4_sw((a),(b),(c))
#endif

// ---------------------------------------------------------------------------
// Prep A: f16-convert W_ih, fuse biases.
// ---------------------------------------------------------------------------
__global__ __launch_bounds__(256) void prep_kernel(
    const float* __restrict__ Wih, const float* __restrict__ bih,
    const float* __restrict__ bhh, _Float16* __restrict__ Wihf,
    float* __restrict__ bias) {
  const int idx = blockIdx.x * 256 + threadIdx.x;     // grid covers 262144
  Wihf[idx] = (_Float16)Wih[idx];
  if (idx < 1024) bias[idx] = bih[idx] + bhh[idx];
}

// ---------------------------------------------------------------------------
// Prep B: quantize W_hh to i8 with per-row scale. One thread per row.
// Wq[k4*1024 + row] packs k = 4*k4 .. 4*k4+3 (k ascending in byte order,
// matching the h-byte packing in the scan). scales[row] = row absmax.
// ---------------------------------------------------------------------------
__global__ __launch_bounds__(256) void wquant_kernel(
    const float* __restrict__ Whh, unsigned int* __restrict__ Wq,
    float* __restrict__ scales) {
  const int r = blockIdx.x * 256 + threadIdx.x;       // 1024 rows, grid = 4
  const float* row = Whh + (size_t)r * 256;
  float m = 0.f;
  #pragma unroll 4
  for (int k = 0; k < 256; ++k) m = fmaxf(m, fabsf(row[k]));
  if (m == 0.f) m = 1e-20f;
  scales[r] = m;
  const float inv = 127.f / m;
  for (int c4 = 0; c4 < 64; ++c4) {
    unsigned int q = 0;
    #pragma unroll
    for (int j = 0; j < 4; ++j) {
      int v = (int)rintf(row[4*c4 + j] * inv);
      q |= ((unsigned int)(unsigned char)(signed char)v) << (8*j);
    }
    Wq[c4*1024 + r] = q;
  }
}

// ---------------------------------------------------------------------------
// Phase 1: x_proj GEMM (f16 MFMA, 128x128 tile). Epilogue stores XP with
// PERMUTED columns: np = 4*(n&255) + (n>>8), so the scan's thread t reads its
// {i,f,g,o} pre-activations for element t as one contiguous 8B half4.
// ---------------------------------------------------------------------------
#define BM 128
#define BN 128
#define BK 32
#define LDA 40

__global__ __launch_bounds__(256) void xproj_gemm(
    const float* __restrict__ X, const _Float16* __restrict__ Wihf,
    const float* __restrict__ bias, _Float16* __restrict__ XP) {
  __shared__ _Float16 As[BM*LDA];
  __shared__ _Float16 Bs[BN*LDA];
  const int tid  = threadIdx.x;
  const int m0   = blockIdx.x * BM;
  const int n0   = blockIdx.y * BN;
  const int lane = tid & 63;
  const int w    = tid >> 6;
  const int wm   = w & 1, wn = w >> 1;
  const int row  = tid >> 1, hlf = tid & 1;   // staging map: 2 threads/row

  f32x4 acc[4][4];
  #pragma unroll
  for (int mi = 0; mi < 4; ++mi)
    #pragma unroll
    for (int ni = 0; ni < 4; ++ni)
      acc[mi][ni] = (f32x4){0.f, 0.f, 0.f, 0.f};

  for (int kt = 0; kt < ISZ/BK; ++kt) {
    const int k0 = kt * BK;
    __syncthreads();
    {
      const float4* pa = (const float4*)(X + (size_t)(m0+row)*ISZ + k0 + hlf*16);
      float4 f0 = pa[0], f1 = pa[1], f2 = pa[2], f3 = pa[3];
      half8 h0, h1;
      h0[0]=(_Float16)f0.x; h0[1]=(_Float16)f0.y; h0[2]=(_Float16)f0.z; h0[3]=(_Float16)f0.w;
      h0[4]=(_Float16)f1.x; h0[5]=(_Float16)f1.y; h0[6]=(_Float16)f1.z; h0[7]=(_Float16)f1.w;
      h1[0]=(_Float16)f2.x; h1[1]=(_Float16)f2.y; h1[2]=(_Float16)f2.z; h1[3]=(_Float16)f2.w;
      h1[4]=(_Float16)f3.x; h1[5]=(_Float16)f3.y; h1[6]=(_Float16)f3.z; h1[7]=(_Float16)f3.w;
      *(half8*)&As[row*LDA + hlf*16]     = h0;
      *(half8*)&As[row*LDA + hlf*16 + 8] = h1;
      const half8* pb = (const half8*)(Wihf + (size_t)(n0+row)*ISZ + k0 + hlf*16);
      half8 b0 = pb[0], b1 = pb[1];
      *(half8*)&Bs[row*LDA + hlf*16]     = b0;
      *(half8*)&Bs[row*LDA + hlf*16 + 8] = b1;
    }
    __syncthreads();
    const int kch = (lane >> 4) * 8;
    const int rm  = wm*64 + (lane & 15);
    const int rn  = wn*64 + (lane & 15);
    half8 af[4], bf[4];
    #pragma unroll
    for (int i = 0; i < 4; ++i) {
      af[i] = *(const half8*)&As[(rm + i*16)*LDA + kch];
      bf[i] = *(const half8*)&Bs[(rn + i*16)*LDA + kch];
    }
    #pragma unroll
    for (int mi = 0; mi < 4; ++mi)
      #pragma unroll
      for (int ni = 0; ni < 4; ++ni)
        acc[mi][ni] = __builtin_amdgcn_mfma_f32_16x16x32_f16(af[mi], bf[ni], acc[mi][ni], 0, 0, 0);
  }
  const int col = lane & 15, qr = (lane >> 4) * 4;
  #pragma unroll
  for (int ni = 0; ni < 4; ++ni) {
    const int n  = n0 + wn*64 + ni*16 + col;
    const int np = ((n & 255) << 2) | (n >> 8);     // gate-interleaved column
    const float bs = bias[n];
    #pragma unroll
    for (int mi = 0; mi < 4; ++mi) {
      #pragma unroll
      for (int r = 0; r < 4; ++r) {
        const int m = m0 + wm*64 + mi*16 + qr + r;
        XP[(size_t)m*G4 + np] = (_Float16)(acc[mi][ni][r] + bs);
      }
    }
  }
}

// ---------------------------------------------------------------------------
// Phase 2: scan, int8. 64 WGs x 256 threads (4 waves, 1/SIMD). Thread t owns
// all 4 gate rows {t,256+t,512+t,768+t} of h-element t -> gates combine
// LOCALLY, one barrier/step. Weights i8: 64 uint4 = 256 dwords/thread ->
// fits the 256-VGPR arch file (overflow goes to AGPR, not scratch; f16
// rounds 1-3 all scratch-spilled, 6.5 ms). h quantized to i8 (scale 127),
// double-buffered in LDS: 16 broadcast b128 reads/thread/step = the only
// LDS traffic (~770 cyc/CU/step vs ~115 KB/step before).
// ---------------------------------------------------------------------------
__global__ __launch_bounds__(256, 1) void lstm_scan(
    const _Float16* __restrict__ XP, const unsigned int* __restrict__ Wq,
    const float* __restrict__ scales, float* __restrict__ out) {
  __shared__ uint4 hq4[2][16];            // h as i8, double-buffered (512 B)
  const int t = threadIdx.x;
  const int b = blockIdx.x;

  // stage weights: wreg[r*16+c].{x,y,z,w} covers row r*256+t, k = 16c..16c+15
  uint4 wreg[64];
  #pragma unroll
  for (int c = 0; c < 16; ++c)
    #pragma unroll
    for (int r = 0; r < 4; ++r) {
      uint4 v;
      v.x = Wq[(4*c+0)*1024 + r*256 + t];
      v.y = Wq[(4*c+1)*1024 + r*256 + t];
      v.z = Wq[(4*c+2)*1024 + r*256 + t];
      v.w = Wq[(4*c+3)*1024 + r*256 + t];
      wreg[r*16 + c] = v;
    }
  float scl[4];
  #pragma unroll
  for (int r = 0; r < 4; ++r) scl[r] = scales[r*256 + t] * (1.f/(127.f*127.f));

  if (t < 16) { hq4[0][t] = (uint4){0,0,0,0}; hq4[1][t] = (uint4){0,0,0,0}; }

  float cst = 0.f;
  const _Float16* xb = XP + (size_t)b*SEQ*G4 + 4*t;
  half4v xp4 = *(const half4v*)xb;        // step-0 pre-activations {i,f,g,o}
  float* outb = out + (size_t)b*SEQ*H + t;
  __syncthreads();

  int cur = 0;
  #pragma unroll 1
  for (int s = 0; s < SEQ; ++s) {
    const int sn = (s + 1 < SEQ) ? (s + 1) : s;
    const half4v xnext = *(const half4v*)(xb + (size_t)sn * G4);  // prefetch

    int a0 = 0, a1 = 0, a2 = 0, a3 = 0;
    const uint4* hb = hq4[cur];
    #pragma unroll
    for (int c = 0; c < 16; ++c) {
      const uint4 hv = hb[c];
      const uint4 w0 = wreg[c], w1 = wreg[16+c], w2 = wreg[32+c], w3 = wreg[48+c];
      a0 = SDOT4(w0.x, hv.x, a0); a0 = SDOT4(w0.y, hv.y, a0);
      a0 = SDOT4(w0.z, hv.z, a0); a0 = SDOT4(w0.w, hv.w, a0);
      a1 = SDOT4(w1.x, hv.x, a1); a1 = SDOT4(w1.y, hv.y, a1);
      a1 = SDOT4(w1.z, hv.z, a1); a1 = SDOT4(w1.w, hv.w, a1);
      a2 = SDOT4(w2.x, hv.x, a2); a2 = SDOT4(w2.y, hv.y, a2);
      a2 = SDOT4(w2.z, hv.z, a2); a2 = SDOT4(w2.w, hv.w, a2);
      a3 = SDOT4(w3.x, hv.x, a3); a3 = SDOT4(w3.y, hv.y, a3);
      a3 = SDOT4(w3.z, hv.z, a3); a3 = SDOT4(w3.w, hv.w, a3);
    }
    const float gi = (float)xp4[0] + (float)a0 * scl[0];
    const float gf = (float)xp4[1] + (float)a1 * scl[1];
    const float gg = (float)xp4[2] + (float)a2 * scl[2];
    const float go = (float)xp4[3] + (float)a3 * scl[3];
    const float si = 1.f / (1.f + __expf(-gi));
    const float sf = 1.f / (1.f + __expf(-gf));
    const float tg = 2.f / (1.f + __expf(-2.f*gg)) - 1.f;
    const float so = 1.f / (1.f + __expf(-go));
    cst = sf*cst + si*tg;
    const float th = 2.f / (1.f + __expf(-2.f*cst)) - 1.f;
    const float h = so*th;
    outb[(size_t)s*H] = h;
    // quantize h for next step, write to NEXT buffer (no WAR hazard)
    const int hq = (int)rintf(h * 127.f);
    ((signed char*)hq4[cur ^ 1])[t] = (signed char)hq;
    if (s == SEQ-1) {
      out[(size_t)BATCH*SEQ*H + (size_t)b*H + t] = h;                     // final h
      out[(size_t)BATCH*SEQ*H + (size_t)BATCH*H + (size_t)b*H + t] = cst; // final c
    }
    xp4 = xnext;
    cur ^= 1;
    __syncthreads();
  }
}

// ---------------------------------------------------------------------------
// ws: [ XP f16 256MB | Wihf f16 512KB | Wq i8 256KB | scales 4KB | bias 4KB ]
// ---------------------------------------------------------------------------
extern "C" void kernel_launch(void* const* d_in, const int* in_sizes, int n_in,
                              void* d_out, int out_size, void* d_ws, size_t ws_size,
                              hipStream_t stream) {
  const float* x   = (const float*)d_in[0];
  const float* Wih = (const float*)d_in[1];
  const float* Whh = (const float*)d_in[2];
  const float* bih = (const float*)d_in[3];
  const float* bhh = (const float*)d_in[4];
  float* out = (float*)d_out;

  char* ws = (char*)d_ws;
  const size_t XP_BYTES = (size_t)M_TOT * G4 * sizeof(_Float16);   // 268435456
  _Float16*     XPp  = (_Float16*)ws;
  _Float16*     Wihf = (_Float16*)(ws + XP_BYTES);
  unsigned int* Wq   = (unsigned int*)(ws + XP_BYTES + 524288);
  float*        scl  = (float*)(ws + XP_BYTES + 786432);
  float*        bias = (float*)(ws + XP_BYTES + 790528);

  prep_kernel  <<<dim3(1024),            dim3(256), 0, stream>>>(Wih, bih, bhh, Wihf, bias);
  wquant_kernel<<<dim3(4),               dim3(256), 0, stream>>>(Whh, Wq, scl);
  xproj_gemm   <<<dim3(M_TOT/BM, G4/BN), dim3(256), 0, stream>>>(x, Wihf, bias, XPp);
  lstm_scan    <<<dim3(BATCH),           dim3(256), 0, stream>>>(XPp, Wq, scl, out);
}